// Round 3
// baseline (446.820 us; speedup 1.0000x reference)
//
#include <hip/hip_runtime.h>
#include <hip/hip_bf16.h>
#include <stdint.h>

#define N_NODES 50000
#define N_EDGES 800000
#define NREL    8
#define NBASES  30
#define DIM     128
#define NKEYS   (N_NODES * NREL)            // 400000 counting-sort buckets (dst*8+type)
#define KFULL   1152                        // 8*128 agg + 128 x
#define SCAN_NB ((NKEYS + 255) / 256)       // 1563 scan blocks

typedef __attribute__((ext_vector_type(8))) short short8;
typedef __attribute__((ext_vector_type(4))) float floatx4;
typedef __hip_bfloat16  bf16;
typedef __hip_bfloat162 bf16x2;

// ---------------- weight prep ----------------
// WfullT[o][k], o in [0,128), k in [0,1152): k<1024 -> W_r[i][o] (r=k>>7,i=k&127); k>=1024 -> root[k-1024][o]
// wrelT/wrootT[o][k] for gemm2.
__global__ void prep_weights(const float* __restrict__ basis, const float* __restrict__ comp,
                             const float* __restrict__ root, const float* __restrict__ w_rel,
                             const float* __restrict__ w_root,
                             bf16* __restrict__ WfullT, bf16* __restrict__ wrelT, bf16* __restrict__ wrootT) {
    int idx = blockIdx.x * blockDim.x + threadIdx.x;
    const int n_full = DIM * KFULL;          // 147456
    const int n_sq   = DIM * DIM;            // 16384
    if (idx < n_full) {
        int k = idx % KFULL, o = idx / KFULL;
        float v;
        if (k < 1024) {
            int r = k >> 7, i = k & 127;
            v = 0.f;
            for (int b = 0; b < NBASES; ++b)
                v += comp[r * NBASES + b] * basis[(b * DIM + i) * DIM + o];
        } else {
            v = root[(k - 1024) * DIM + o];
        }
        WfullT[o * KFULL + k] = __float2bfloat16(v);
    } else if (idx < n_full + n_sq) {
        int t = idx - n_full; int k = t & 127, o = t >> 7;
        wrelT[o * DIM + k] = __float2bfloat16(w_rel[k * DIM + o]);
    } else if (idx < n_full + 2 * n_sq) {
        int t = idx - n_full - n_sq; int k = t & 127, o = t >> 7;
        wrootT[o * DIM + k] = __float2bfloat16(w_root[k * DIM + o]);
    }
}

// ---------------- fp32 -> bf16 node features ----------------
__global__ void conv_x(const float* __restrict__ x, bf16* __restrict__ xb, int n) {
    int i = blockIdx.x * blockDim.x + threadIdx.x;
    if (i < n) xb[i] = __float2bfloat16(x[i]);
}

// ---------------- counting sort by (dst*8+type) ----------------
__global__ void hist_kernel(const int* __restrict__ ei, const int* __restrict__ et,
                            int* __restrict__ deg) {
    int e = blockIdx.x * blockDim.x + threadIdx.x;
    if (e < N_EDGES) atomicAdd(&deg[ei[N_EDGES + e] * NREL + et[e]], 1);
}

// Phase 1: per-block inclusive scan of deg -> segoff[i+1] (local), block total -> bsum[b]
__global__ void scan_blocks(const int* __restrict__ deg, int* __restrict__ segoff,
                            int* __restrict__ bsum, int n) {
    __shared__ int buf[256];
    int tid = threadIdx.x;
    int i = blockIdx.x * 256 + tid;
    int v = (i < n) ? deg[i] : 0;
    buf[tid] = v;
    __syncthreads();
#pragma unroll
    for (int o = 1; o < 256; o <<= 1) {
        int t = (tid >= o) ? buf[tid - o] : 0;
        __syncthreads();
        buf[tid] += t;
        __syncthreads();
    }
    if (i < n) segoff[i + 1] = buf[tid];
    if (tid == 255) bsum[blockIdx.x] = buf[255];
}

// Phase 2: single WAVE shuffle-scan of block sums into EXCLUSIVE offsets (no barriers)
__global__ void scan_sums(int* __restrict__ bsum, int nb) {
    int lane = threadIdx.x;   // 64 threads
    int base = 0;
    for (int start = 0; start < nb; start += 64) {
        int i = start + lane;
        int v = (i < nb) ? bsum[i] : 0;
        int incl = v;
#pragma unroll
        for (int o = 1; o < 64; o <<= 1) {
            int t = __shfl_up(incl, o, 64);
            if (lane >= o) incl += t;
        }
        if (i < nb) bsum[i] = base + incl - v;   // exclusive
        base += __shfl(incl, 63, 64);
    }
}

// Phase 3: add block offsets; set segoff[0]=0
__global__ void scan_add(int* __restrict__ segoff, const int* __restrict__ bsum, int n) {
    int i = blockIdx.x * 256 + threadIdx.x;
    if (i < n) segoff[i + 1] += bsum[blockIdx.x];
    if (i == 0) segoff[0] = 0;
}

__global__ void scatter_kernel(const int* __restrict__ ei, const int* __restrict__ et,
                               const float* __restrict__ en, const int* __restrict__ segoff,
                               int* __restrict__ cur, uint2* __restrict__ rec) {
    int e = blockIdx.x * blockDim.x + threadIdx.x;
    if (e < N_EDGES) {
        int key = ei[N_EDGES + e] * NREL + et[e];
        int p = segoff[key] + atomicAdd(&cur[key], 1);
        rec[p] = make_uint2((unsigned)ei[e], __float_as_uint(en[e]));
    }
}

// ---------------- typed aggregation: agg[n][t][:] = sum_{e in (n,t)} norm_e * xb[src_e] ----------------
// Records sorted by (dst,type): wave walks 8 contiguous subsegments, 2 FMA/edge/lane.
__global__ void agg1_kernel(const uint2* __restrict__ rec, const int* __restrict__ segoff,
                            const bf16x2* __restrict__ xb2, bf16x2* __restrict__ agg2) {
    int node = blockIdx.x * 4 + (threadIdx.x >> 6);
    if (node >= N_NODES) return;
    int lane = threadIdx.x & 63;
    int base = node * NREL;
    for (int t = 0; t < NREL; ++t) {
        int s = segoff[base + t], e = segoff[base + t + 1];
        float ax = 0.f, ay = 0.f;
        for (int i = s; i < e; ++i) {
            uint2 r = rec[i];
            float norm = __uint_as_float(r.y);
            bf16x2 v = xb2[r.x * 64u + lane];
            ax += norm * __bfloat162float(v.x);
            ay += norm * __bfloat162float(v.y);
        }
        bf16x2 o;
        o.x = __float2bfloat16(ax);
        o.y = __float2bfloat16(ay);
        agg2[(unsigned)(base + t) * 64u + lane] = o;
    }
}

// ---------------- GEMM: h[M,128](bf16) = [agg | xb][M,1152] @ WfullT^T + bias1 ----------------
__global__ __launch_bounds__(256) void gemm_h(const bf16* __restrict__ agg, const bf16* __restrict__ xb,
                                              const bf16* __restrict__ WfullT, const float* __restrict__ bias1,
                                              bf16* __restrict__ h, int M) {
    __shared__ ushort As[64][72];    // 64 m-rows x 64 k  (+8 pad: row stride 144B -> 4-bank shift, 2-way free)
    __shared__ ushort Bs[128][72];   // 128 out-cols x 64 k
    const ushort* Au_agg = (const ushort*)agg;
    const ushort* Au_x   = (const ushort*)xb;
    const ushort* Bu     = (const ushort*)WfullT;
    int tm = blockIdx.x * 64;
    int wave = threadIdx.x >> 6, lane = threadIdx.x & 63;
    int q = lane >> 4, mr = lane & 15;
    floatx4 zero = {0.f, 0.f, 0.f, 0.f};
    floatx4 acc[8] = {zero, zero, zero, zero, zero, zero, zero, zero};

    for (int kt = 0; kt < 18; ++kt) {
        if (kt) __syncthreads();
        // stage A: 64x64 elems = 512 short8 -> 2 per thread
#pragma unroll
        for (int u = 0; u < 2; ++u) {
            int cc = threadIdx.x + u * 256;
            int row = cc >> 3, seg = cc & 7;
            int gr = tm + row;
            short8 av = {0, 0, 0, 0, 0, 0, 0, 0};
            if (gr < M) {
                if (kt < 16) av = *(const short8*)(Au_agg + (size_t)gr * 1024 + kt * 64 + seg * 8);
                else         av = *(const short8*)(Au_x   + (size_t)gr * 128 + (kt - 16) * 64 + seg * 8);
            }
            *(short8*)(&As[row][seg * 8]) = av;
        }
        // stage B: 128x64 elems = 1024 short8 -> 4 per thread
#pragma unroll
        for (int u = 0; u < 4; ++u) {
            int cc = threadIdx.x + u * 256;
            int row = cc >> 3, seg = cc & 7;
            short8 bv = *(const short8*)(Bu + (size_t)row * KFULL + kt * 64 + seg * 8);
            *(short8*)(&Bs[row][seg * 8]) = bv;
        }
        __syncthreads();
#pragma unroll
        for (int kh = 0; kh < 2; ++kh) {
            short8 a = *(const short8*)(&As[wave * 16 + mr][q * 8 + kh * 32]);
#pragma unroll
            for (int nt = 0; nt < 8; ++nt) {
                short8 b = *(const short8*)(&Bs[nt * 16 + mr][q * 8 + kh * 32]);
                acc[nt] = __builtin_amdgcn_mfma_f32_16x16x32_bf16(a, b, acc[nt], 0, 0, 0);
            }
        }
    }
#pragma unroll
    for (int nt = 0; nt < 8; ++nt)
#pragma unroll
        for (int r4 = 0; r4 < 4; ++r4) {
            int row = tm + wave * 16 + q * 4 + r4;
            int col = nt * 16 + mr;
            if (row < M) h[(size_t)row * 128 + col] = __float2bfloat16(acc[nt][r4] + bias1[col]);
        }
}

// ---------------- layer-2 segment sum: agg2nd = seg_sum(h[src]) over full node segment ----------------
__global__ void seg2_kernel(const uint2* __restrict__ rec, const int* __restrict__ segoff,
                            const bf16x2* __restrict__ h2, bf16x2* __restrict__ out2) {
    int node = blockIdx.x * 4 + (threadIdx.x >> 6);
    if (node >= N_NODES) return;
    int lane = threadIdx.x & 63;
    int s = segoff[node * NREL], e = segoff[node * NREL + NREL];
    float a0 = 0.f, a1 = 0.f;
    for (int i = s; i < e; ++i) {
        bf16x2 v = h2[rec[i].x * 64u + lane];
        a0 += __bfloat162float(v.x);
        a1 += __bfloat162float(v.y);
    }
    bf16x2 o;
    o.x = __float2bfloat16(a0);
    o.y = __float2bfloat16(a1);
    out2[node * 64 + lane] = o;
}

// ---------------- final GEMM: out[M,128](f32) = agg2nd@w_rel + h@w_root + b_rel ----------------
__global__ __launch_bounds__(256) void gemm2_kernel(const bf16* __restrict__ A1, const bf16* __restrict__ B1T,
                                                    const bf16* __restrict__ A2, const bf16* __restrict__ B2T,
                                                    const float* __restrict__ brel, float* __restrict__ out, int M) {
    __shared__ ushort As[64][136];
    __shared__ ushort Bs[64][136];
    int tm = blockIdx.x * 64, tn = blockIdx.y * 64;
    int wave = threadIdx.x >> 6, lane = threadIdx.x & 63;
    int q = lane >> 4, mr = lane & 15;
    floatx4 zero = {0.f, 0.f, 0.f, 0.f};
    floatx4 acc[4] = {zero, zero, zero, zero};

    for (int phase = 0; phase < 2; ++phase) {
        const ushort* Au = (const ushort*)(phase ? A2 : A1);
        const ushort* Bu = (const ushort*)(phase ? B2T : B1T);
        if (phase) __syncthreads();
        for (int c = threadIdx.x; c < 64 * 16; c += 256) {
            int row = c >> 4, seg = c & 15;
            int gr = tm + row;
            short8 av = {0, 0, 0, 0, 0, 0, 0, 0};
            if (gr < M) av = *(const short8*)(Au + (size_t)gr * 128 + seg * 8);
            *(short8*)(&As[row][seg * 8]) = av;
            short8 bv = *(const short8*)(Bu + (size_t)(tn + row) * 128 + seg * 8);
            *(short8*)(&Bs[row][seg * 8]) = bv;
        }
        __syncthreads();
#pragma unroll
        for (int kt = 0; kt < 4; ++kt) {
            short8 a = *(const short8*)(&As[wave * 16 + mr][q * 8 + kt * 32]);
#pragma unroll
            for (int nt = 0; nt < 4; ++nt) {
                short8 b = *(const short8*)(&Bs[nt * 16 + mr][q * 8 + kt * 32]);
                acc[nt] = __builtin_amdgcn_mfma_f32_16x16x32_bf16(a, b, acc[nt], 0, 0, 0);
            }
        }
    }
#pragma unroll
    for (int nt = 0; nt < 4; ++nt)
#pragma unroll
        for (int r4 = 0; r4 < 4; ++r4) {
            int row = tm + wave * 16 + q * 4 + r4;
            int col = tn + nt * 16 + mr;
            if (row < M) out[(size_t)row * 128 + col] = acc[nt][r4] + brel[col];
        }
}

extern "C" void kernel_launch(void* const* d_in, const int* in_sizes, int n_in,
                              void* d_out, int out_size, void* d_ws, size_t ws_size,
                              hipStream_t stream) {
    const float* x      = (const float*)d_in[0];
    const int*   ei     = (const int*)d_in[1];
    const int*   et     = (const int*)d_in[2];
    const float* en     = (const float*)d_in[3];
    const float* basis  = (const float*)d_in[4];
    const float* comp   = (const float*)d_in[5];
    const float* root   = (const float*)d_in[6];
    const float* bias1  = (const float*)d_in[7];
    const float* w_rel  = (const float*)d_in[8];
    const float* b_rel  = (const float*)d_in[9];
    const float* w_root = (const float*)d_in[10];
    float* out = (float*)d_out;

    char* ws = (char*)d_ws;
    size_t off = 0;
    auto alloc = [&](size_t bytes) { size_t o = off; off += (bytes + 255) & ~(size_t)255; return o; };

    size_t o_deg    = alloc((size_t)NKEYS * 4);      // zeroed
    size_t o_cur    = alloc((size_t)NKEYS * 4);      // zeroed (contiguous with deg)
    size_t o_segoff = alloc((size_t)(NKEYS + 1) * 4);
    size_t o_bsum   = alloc((size_t)SCAN_NB * 4);
    size_t o_rec    = alloc((size_t)N_EDGES * 8);
    size_t o_wfull  = alloc((size_t)DIM * KFULL * 2);
    size_t o_wrel   = alloc((size_t)DIM * DIM * 2);
    size_t o_wroot  = alloc((size_t)DIM * DIM * 2);
    size_t o_xb     = alloc((size_t)N_NODES * DIM * 2);
    size_t o_agg    = alloc((size_t)N_NODES * NREL * DIM * 2);   // 102.4 MB
    size_t o_hb     = alloc((size_t)N_NODES * DIM * 2);
    size_t o_agg2   = alloc((size_t)N_NODES * DIM * 2);

    int*   deg    = (int*)(ws + o_deg);
    int*   cur    = (int*)(ws + o_cur);
    int*   segoff = (int*)(ws + o_segoff);
    int*   bsum   = (int*)(ws + o_bsum);
    uint2* rec    = (uint2*)(ws + o_rec);
    bf16*  wfull  = (bf16*)(ws + o_wfull);
    bf16*  wrelT  = (bf16*)(ws + o_wrel);
    bf16*  wrootT = (bf16*)(ws + o_wroot);
    bf16*  xb     = (bf16*)(ws + o_xb);
    bf16*  agg    = (bf16*)(ws + o_agg);
    bf16*  hb     = (bf16*)(ws + o_hb);
    bf16*  agg2   = (bf16*)(ws + o_agg2);

    // zero deg + cur (contiguous, padded sizes are 256-multiples)
    hipMemsetAsync(ws + o_deg, 0, o_segoff - o_deg, stream);

    {   // weights
        int total = DIM * KFULL + 2 * DIM * DIM;
        prep_weights<<<(total + 255) / 256, 256, 0, stream>>>(basis, comp, root, w_rel, w_root,
                                                              wfull, wrelT, wrootT);
    }
    {   // bf16 features
        int n = N_NODES * DIM;
        conv_x<<<(n + 255) / 256, 256, 0, stream>>>(x, xb, n);
    }
    // counting sort by (dst*8+type)
    hist_kernel<<<(N_EDGES + 255) / 256, 256, 0, stream>>>(ei, et, deg);
    scan_blocks<<<SCAN_NB, 256, 0, stream>>>(deg, segoff, bsum, NKEYS);
    scan_sums<<<1, 64, 0, stream>>>(bsum, SCAN_NB);
    scan_add<<<SCAN_NB, 256, 0, stream>>>(segoff, bsum, NKEYS);
    scatter_kernel<<<(N_EDGES + 255) / 256, 256, 0, stream>>>(ei, et, en, segoff, cur, rec);

    // typed aggregation (gather from L2-resident xb)
    agg1_kernel<<<(N_NODES + 3) / 4, 256, 0, stream>>>(rec, segoff, (const bf16x2*)xb, (bf16x2*)agg);
    // h = [agg | xb] @ Wfull + bias1
    gemm_h<<<(N_NODES + 63) / 64, 256, 0, stream>>>(agg, xb, wfull, bias1, hb, N_NODES);
    // layer 2 aggregation (gather from L2-resident hb)
    seg2_kernel<<<(N_NODES + 3) / 4, 256, 0, stream>>>(rec, segoff, (const bf16x2*)hb, (bf16x2*)agg2);
    // out = agg2 @ w_rel + h @ w_root + b_rel
    {
        dim3 grid((N_NODES + 63) / 64, DIM / 64);
        gemm2_kernel<<<grid, 256, 0, stream>>>(agg2, wrelT, hb, wrootT, b_rel, out, N_NODES);
    }
}

// Round 4
// 425.321 us; speedup vs baseline: 1.0505x; 1.0505x over previous
//
#include <hip/hip_runtime.h>
#include <hip/hip_bf16.h>
#include <stdint.h>

#define N_NODES 50000
#define N_EDGES 800000
#define NREL    8
#define NBASES  30
#define DIM     128
#define NKEYS   (N_NODES * NREL)            // 400000 counting-sort buckets (dst*8+type)
#define KFULL   1152                        // 8*128 agg + 128 x
#define SCAN_NB ((NKEYS + 255) / 256)       // 1563 scan blocks

typedef __attribute__((ext_vector_type(8))) short short8;
typedef __attribute__((ext_vector_type(4))) float floatx4;
typedef __hip_bfloat16  bf16;
typedef __hip_bfloat162 bf16x2;

__device__ inline ushort f2bu(float f) { bf16 b = __float2bfloat16(f); return *(ushort*)&b; }

// ---------------- weight prep ----------------
__global__ void prep_weights(const float* __restrict__ basis, const float* __restrict__ comp,
                             const float* __restrict__ root, const float* __restrict__ w_rel,
                             const float* __restrict__ w_root,
                             bf16* __restrict__ WfullT, bf16* __restrict__ wrelT, bf16* __restrict__ wrootT) {
    int idx = blockIdx.x * blockDim.x + threadIdx.x;
    const int n_full = DIM * KFULL;          // 147456
    const int n_sq   = DIM * DIM;            // 16384
    if (idx < n_full) {
        int k = idx % KFULL, o = idx / KFULL;
        float v;
        if (k < 1024) {
            int r = k >> 7, i = k & 127;
            v = 0.f;
            for (int b = 0; b < NBASES; ++b)
                v += comp[r * NBASES + b] * basis[(b * DIM + i) * DIM + o];
        } else {
            v = root[(k - 1024) * DIM + o];
        }
        WfullT[o * KFULL + k] = __float2bfloat16(v);
    } else if (idx < n_full + n_sq) {
        int t = idx - n_full; int k = t & 127, o = t >> 7;
        wrelT[o * DIM + k] = __float2bfloat16(w_rel[k * DIM + o]);
    } else if (idx < n_full + 2 * n_sq) {
        int t = idx - n_full - n_sq; int k = t & 127, o = t >> 7;
        wrootT[o * DIM + k] = __float2bfloat16(w_root[k * DIM + o]);
    }
}

// ---------------- fp32 -> bf16 node features (vectorized x4) ----------------
__global__ void conv_x(const float4* __restrict__ x4, ushort4* __restrict__ xb4, int n4) {
    int i = blockIdx.x * blockDim.x + threadIdx.x;
    if (i < n4) {
        float4 f = x4[i];
        ushort4 o;
        o.x = f2bu(f.x); o.y = f2bu(f.y); o.z = f2bu(f.z); o.w = f2bu(f.w);
        xb4[i] = o;
    }
}

// ---------------- counting sort by (dst*8+type) ----------------
__global__ void hist_kernel(const int* __restrict__ ei, const int* __restrict__ et,
                            int* __restrict__ deg) {
    int e = blockIdx.x * blockDim.x + threadIdx.x;
    if (e < N_EDGES) atomicAdd(&deg[ei[N_EDGES + e] * NREL + et[e]], 1);
}

__global__ void scan_blocks(const int* __restrict__ deg, int* __restrict__ segoff,
                            int* __restrict__ bsum, int n) {
    __shared__ int buf[256];
    int tid = threadIdx.x;
    int i = blockIdx.x * 256 + tid;
    int v = (i < n) ? deg[i] : 0;
    buf[tid] = v;
    __syncthreads();
#pragma unroll
    for (int o = 1; o < 256; o <<= 1) {
        int t = (tid >= o) ? buf[tid - o] : 0;
        __syncthreads();
        buf[tid] += t;
        __syncthreads();
    }
    if (i < n) segoff[i + 1] = buf[tid];
    if (tid == 255) bsum[blockIdx.x] = buf[255];
}

// single WAVE shuffle-scan of block sums -> exclusive (no barriers)
__global__ void scan_sums(int* __restrict__ bsum, int nb) {
    int lane = threadIdx.x;   // 64 threads
    int base = 0;
    for (int start = 0; start < nb; start += 64) {
        int i = start + lane;
        int v = (i < nb) ? bsum[i] : 0;
        int incl = v;
#pragma unroll
        for (int o = 1; o < 64; o <<= 1) {
            int t = __shfl_up(incl, o, 64);
            if (lane >= o) incl += t;
        }
        if (i < nb) bsum[i] = base + incl - v;   // exclusive
        base += __shfl(incl, 63, 64);
    }
}

__global__ void scan_add(int* __restrict__ segoff, const int* __restrict__ bsum, int n) {
    int i = blockIdx.x * 256 + threadIdx.x;
    if (i < n) segoff[i + 1] += bsum[blockIdx.x];
    if (i == 0) segoff[0] = 0;
}

// rec.x = src | (type<<16)
__global__ void scatter_kernel(const int* __restrict__ ei, const int* __restrict__ et,
                               const float* __restrict__ en, const int* __restrict__ segoff,
                               int* __restrict__ cur, uint2* __restrict__ rec) {
    int e = blockIdx.x * blockDim.x + threadIdx.x;
    if (e < N_EDGES) {
        int typ = et[e];
        int key = ei[N_EDGES + e] * NREL + typ;
        int p = segoff[key] + atomicAdd(&cur[key], 1);
        rec[p] = make_uint2((unsigned)ei[e] | ((unsigned)typ << 16), __float_as_uint(en[e]));
    }
}

// ---------------- typed aggregation, 4-deep pipelined gather ----------------
// Walk the node's whole segment (sorted by type); flush accumulator at type boundaries.
__global__ void agg1_kernel(const uint2* __restrict__ rec, const int* __restrict__ segoff,
                            const bf16x2* __restrict__ xb2, bf16x2* __restrict__ agg2) {
    int node = blockIdx.x * 4 + (threadIdx.x >> 6);
    if (node >= N_NODES) return;
    int lane = threadIdx.x & 63;
    int base = node * NREL;
    int s = segoff[base], e = segoff[base + NREL];
    float ax = 0.f, ay = 0.f;
    int cur_t = 0;
    bf16x2 z; z.x = __float2bfloat16(0.f); z.y = __float2bfloat16(0.f);
    for (int chunk = s; chunk < e; chunk += 4) {
        int m = e - chunk; if (m > 4) m = 4;
        uint2 rr[4]; bf16x2 vv[4];
#pragma unroll
        for (int j = 0; j < 4; ++j) if (j < m) rr[j] = rec[chunk + j];
#pragma unroll
        for (int j = 0; j < 4; ++j) if (j < m) vv[j] = xb2[(rr[j].x & 0xFFFFu) * 64u + lane];
#pragma unroll
        for (int j = 0; j < 4; ++j) if (j < m) {
            int t = (int)(rr[j].x >> 16);
            if (t != cur_t) {        // wave-uniform, monotone increasing
                bf16x2 o; o.x = __float2bfloat16(ax); o.y = __float2bfloat16(ay);
                agg2[(unsigned)(base + cur_t) * 64u + lane] = o;
                for (int tt = cur_t + 1; tt < t; ++tt)
                    agg2[(unsigned)(base + tt) * 64u + lane] = z;
                ax = 0.f; ay = 0.f; cur_t = t;
            }
            float norm = __uint_as_float(rr[j].y);
            ax += norm * __bfloat162float(vv[j].x);
            ay += norm * __bfloat162float(vv[j].y);
        }
    }
    {   // final flush + trailing zeros (also handles degree-0 nodes)
        bf16x2 o; o.x = __float2bfloat16(ax); o.y = __float2bfloat16(ay);
        agg2[(unsigned)(base + cur_t) * 64u + lane] = o;
        for (int tt = cur_t + 1; tt < NREL; ++tt)
            agg2[(unsigned)(base + tt) * 64u + lane] = z;
    }
}

// ---------------- GEMM: h[M,128](bf16) = [agg | xb][M,1152] @ WfullT^T + bias1 ----------------
__global__ __launch_bounds__(256) void gemm_h(const bf16* __restrict__ agg, const bf16* __restrict__ xb,
                                              const bf16* __restrict__ WfullT, const float* __restrict__ bias1,
                                              bf16* __restrict__ h, int M) {
    __shared__ ushort As[64][72];
    __shared__ ushort Bs[128][72];
    const ushort* Au_agg = (const ushort*)agg;
    const ushort* Au_x   = (const ushort*)xb;
    const ushort* Bu     = (const ushort*)WfullT;
    int tm = blockIdx.x * 64;
    int wave = threadIdx.x >> 6, lane = threadIdx.x & 63;
    int q = lane >> 4, mr = lane & 15;
    floatx4 zero = {0.f, 0.f, 0.f, 0.f};
    floatx4 acc[8] = {zero, zero, zero, zero, zero, zero, zero, zero};

    for (int kt = 0; kt < 18; ++kt) {
        if (kt) __syncthreads();
#pragma unroll
        for (int u = 0; u < 2; ++u) {
            int cc = threadIdx.x + u * 256;
            int row = cc >> 3, seg = cc & 7;
            int gr = tm + row;
            short8 av = {0, 0, 0, 0, 0, 0, 0, 0};
            if (gr < M) {
                if (kt < 16) av = *(const short8*)(Au_agg + (size_t)gr * 1024 + kt * 64 + seg * 8);
                else         av = *(const short8*)(Au_x   + (size_t)gr * 128 + (kt - 16) * 64 + seg * 8);
            }
            *(short8*)(&As[row][seg * 8]) = av;
        }
#pragma unroll
        for (int u = 0; u < 4; ++u) {
            int cc = threadIdx.x + u * 256;
            int row = cc >> 3, seg = cc & 7;
            short8 bv = *(const short8*)(Bu + (size_t)row * KFULL + kt * 64 + seg * 8);
            *(short8*)(&Bs[row][seg * 8]) = bv;
        }
        __syncthreads();
#pragma unroll
        for (int kh = 0; kh < 2; ++kh) {
            short8 a = *(const short8*)(&As[wave * 16 + mr][q * 8 + kh * 32]);
#pragma unroll
            for (int nt = 0; nt < 8; ++nt) {
                short8 b = *(const short8*)(&Bs[nt * 16 + mr][q * 8 + kh * 32]);
                acc[nt] = __builtin_amdgcn_mfma_f32_16x16x32_bf16(a, b, acc[nt], 0, 0, 0);
            }
        }
    }
#pragma unroll
    for (int nt = 0; nt < 8; ++nt)
#pragma unroll
        for (int r4 = 0; r4 < 4; ++r4) {
            int row = tm + wave * 16 + q * 4 + r4;
            int col = nt * 16 + mr;
            if (row < M) h[(size_t)row * 128 + col] = __float2bfloat16(acc[nt][r4] + bias1[col]);
        }
}

// ---------------- layer-2 segment sum, 8-deep pipelined gather ----------------
__global__ void seg2_kernel(const uint2* __restrict__ rec, const int* __restrict__ segoff,
                            const bf16x2* __restrict__ h2, bf16x2* __restrict__ out2) {
    int node = blockIdx.x * 4 + (threadIdx.x >> 6);
    if (node >= N_NODES) return;
    int lane = threadIdx.x & 63;
    int s = segoff[node * NREL], e = segoff[node * NREL + NREL];
    float a0 = 0.f, a1 = 0.f;
    for (int chunk = s; chunk < e; chunk += 8) {
        int m = e - chunk; if (m > 8) m = 8;
        unsigned ss[8]; bf16x2 vv[8];
#pragma unroll
        for (int j = 0; j < 8; ++j) if (j < m) ss[j] = rec[chunk + j].x & 0xFFFFu;
#pragma unroll
        for (int j = 0; j < 8; ++j) if (j < m) vv[j] = h2[ss[j] * 64u + lane];
#pragma unroll
        for (int j = 0; j < 8; ++j) if (j < m) {
            a0 += __bfloat162float(vv[j].x);
            a1 += __bfloat162float(vv[j].y);
        }
    }
    bf16x2 o;
    o.x = __float2bfloat16(a0);
    o.y = __float2bfloat16(a1);
    out2[node * 64 + lane] = o;
}

// ---------------- final GEMM: out[M,128](f32) = agg2nd@w_rel + h@w_root + b_rel ----------------
__global__ __launch_bounds__(256) void gemm2_kernel(const bf16* __restrict__ A1, const bf16* __restrict__ B1T,
                                                    const bf16* __restrict__ A2, const bf16* __restrict__ B2T,
                                                    const float* __restrict__ brel, float* __restrict__ out, int M) {
    __shared__ ushort As[64][136];
    __shared__ ushort Bs[64][136];
    int tm = blockIdx.x * 64, tn = blockIdx.y * 64;
    int wave = threadIdx.x >> 6, lane = threadIdx.x & 63;
    int q = lane >> 4, mr = lane & 15;
    floatx4 zero = {0.f, 0.f, 0.f, 0.f};
    floatx4 acc[4] = {zero, zero, zero, zero};

    for (int phase = 0; phase < 2; ++phase) {
        const ushort* Au = (const ushort*)(phase ? A2 : A1);
        const ushort* Bu = (const ushort*)(phase ? B2T : B1T);
        if (phase) __syncthreads();
        for (int c = threadIdx.x; c < 64 * 16; c += 256) {
            int row = c >> 4, seg = c & 15;
            int gr = tm + row;
            short8 av = {0, 0, 0, 0, 0, 0, 0, 0};
            if (gr < M) av = *(const short8*)(Au + (size_t)gr * 128 + seg * 8);
            *(short8*)(&As[row][seg * 8]) = av;
            short8 bv = *(const short8*)(Bu + (size_t)(tn + row) * 128 + seg * 8);
            *(short8*)(&Bs[row][seg * 8]) = bv;
        }
        __syncthreads();
#pragma unroll
        for (int kt = 0; kt < 4; ++kt) {
            short8 a = *(const short8*)(&As[wave * 16 + mr][q * 8 + kt * 32]);
#pragma unroll
            for (int nt = 0; nt < 4; ++nt) {
                short8 b = *(const short8*)(&Bs[nt * 16 + mr][q * 8 + kt * 32]);
                acc[nt] = __builtin_amdgcn_mfma_f32_16x16x32_bf16(a, b, acc[nt], 0, 0, 0);
            }
        }
    }
#pragma unroll
    for (int nt = 0; nt < 4; ++nt)
#pragma unroll
        for (int r4 = 0; r4 < 4; ++r4) {
            int row = tm + wave * 16 + q * 4 + r4;
            int col = tn + nt * 16 + mr;
            if (row < M) out[(size_t)row * 128 + col] = acc[nt][r4] + brel[col];
        }
}

extern "C" void kernel_launch(void* const* d_in, const int* in_sizes, int n_in,
                              void* d_out, int out_size, void* d_ws, size_t ws_size,
                              hipStream_t stream) {
    const float* x      = (const float*)d_in[0];
    const int*   ei     = (const int*)d_in[1];
    const int*   et     = (const int*)d_in[2];
    const float* en     = (const float*)d_in[3];
    const float* basis  = (const float*)d_in[4];
    const float* comp   = (const float*)d_in[5];
    const float* root   = (const float*)d_in[6];
    const float* bias1  = (const float*)d_in[7];
    const float* w_rel  = (const float*)d_in[8];
    const float* b_rel  = (const float*)d_in[9];
    const float* w_root = (const float*)d_in[10];
    float* out = (float*)d_out;

    char* ws = (char*)d_ws;
    size_t off = 0;
    auto alloc = [&](size_t bytes) { size_t o = off; off += (bytes + 255) & ~(size_t)255; return o; };

    size_t o_deg    = alloc((size_t)NKEYS * 4);      // zeroed
    size_t o_cur    = alloc((size_t)NKEYS * 4);      // zeroed (contiguous with deg)
    size_t o_segoff = alloc((size_t)(NKEYS + 1) * 4);
    size_t o_bsum   = alloc((size_t)SCAN_NB * 4);
    size_t o_rec    = alloc((size_t)N_EDGES * 8);
    size_t o_wfull  = alloc((size_t)DIM * KFULL * 2);
    size_t o_wrel   = alloc((size_t)DIM * DIM * 2);
    size_t o_wroot  = alloc((size_t)DIM * DIM * 2);
    size_t o_xb     = alloc((size_t)N_NODES * DIM * 2);
    size_t o_agg    = alloc((size_t)N_NODES * NREL * DIM * 2);   // 102.4 MB
    size_t o_hb     = alloc((size_t)N_NODES * DIM * 2);
    size_t o_agg2   = alloc((size_t)N_NODES * DIM * 2);

    int*   deg    = (int*)(ws + o_deg);
    int*   cur    = (int*)(ws + o_cur);
    int*   segoff = (int*)(ws + o_segoff);
    int*   bsum   = (int*)(ws + o_bsum);
    uint2* rec    = (uint2*)(ws + o_rec);
    bf16*  wfull  = (bf16*)(ws + o_wfull);
    bf16*  wrelT  = (bf16*)(ws + o_wrel);
    bf16*  wrootT = (bf16*)(ws + o_wroot);
    bf16*  xb     = (bf16*)(ws + o_xb);
    bf16*  agg    = (bf16*)(ws + o_agg);
    bf16*  hb     = (bf16*)(ws + o_hb);
    bf16*  agg2   = (bf16*)(ws + o_agg2);

    hipMemsetAsync(ws + o_deg, 0, o_segoff - o_deg, stream);

    {   // weights
        int total = DIM * KFULL + 2 * DIM * DIM;
        prep_weights<<<(total + 255) / 256, 256, 0, stream>>>(basis, comp, root, w_rel, w_root,
                                                              wfull, wrelT, wrootT);
    }
    {   // bf16 features (x4 vectorized)
        int n4 = N_NODES * DIM / 4;
        conv_x<<<(n4 + 255) / 256, 256, 0, stream>>>((const float4*)x, (ushort4*)xb, n4);
    }
    // counting sort by (dst*8+type)
    hist_kernel<<<(N_EDGES + 255) / 256, 256, 0, stream>>>(ei, et, deg);
    scan_blocks<<<SCAN_NB, 256, 0, stream>>>(deg, segoff, bsum, NKEYS);
    scan_sums<<<1, 64, 0, stream>>>(bsum, SCAN_NB);
    scan_add<<<SCAN_NB, 256, 0, stream>>>(segoff, bsum, NKEYS);
    scatter_kernel<<<(N_EDGES + 255) / 256, 256, 0, stream>>>(ei, et, en, segoff, cur, rec);

    // typed aggregation (pipelined gather)
    agg1_kernel<<<(N_NODES + 3) / 4, 256, 0, stream>>>(rec, segoff, (const bf16x2*)xb, (bf16x2*)agg);
    // h = [agg | xb] @ Wfull + bias1
    gemm_h<<<(N_NODES + 63) / 64, 256, 0, stream>>>(agg, xb, wfull, bias1, hb, N_NODES);
    // layer 2 aggregation (pipelined gather)
    seg2_kernel<<<(N_NODES + 3) / 4, 256, 0, stream>>>(rec, segoff, (const bf16x2*)hb, (bf16x2*)agg2);
    // out = agg2 @ w_rel + h @ w_root + b_rel
    {
        dim3 grid((N_NODES + 63) / 64, DIM / 64);
        gemm2_kernel<<<grid, 256, 0, stream>>>(agg2, wrelT, hb, wrootT, b_rel, out, N_NODES);
    }
}

// Round 5
// 364.470 us; speedup vs baseline: 1.2259x; 1.1670x over previous
//
#include <hip/hip_runtime.h>
#include <hip/hip_bf16.h>
#include <stdint.h>

#define N_NODES 50000
#define N_EDGES 800000
#define NREL    8
#define NBASES  30
#define DIM     128
#define NKEYS   (N_NODES * NREL)            // 400000 counting-sort buckets (dst*8+type)
#define KFULL   1152                        // 8*128 agg + 128 x
#define SCAN_NB ((NKEYS + 255) / 256)       // 1563 scan blocks

typedef __attribute__((ext_vector_type(8))) short short8;
typedef __attribute__((ext_vector_type(4))) float floatx4;
typedef __hip_bfloat16  bf16;
typedef __hip_bfloat162 bf16x2;

__device__ inline ushort f2bu(float f) { bf16 b = __float2bfloat16(f); return *(ushort*)&b; }
__device__ inline float  bu2f(ushort u) { union { unsigned i; float f; } c; c.i = ((unsigned)u) << 16; return c.f; }

// ---------------- weight prep ----------------
__global__ void prep_weights(const float* __restrict__ basis, const float* __restrict__ comp,
                             const float* __restrict__ root, const float* __restrict__ w_rel,
                             const float* __restrict__ w_root,
                             bf16* __restrict__ WfullT, bf16* __restrict__ wrelT, bf16* __restrict__ wrootT) {
    int idx = blockIdx.x * blockDim.x + threadIdx.x;
    const int n_full = DIM * KFULL;          // 147456
    const int n_sq   = DIM * DIM;            // 16384
    if (idx < n_full) {
        int k = idx % KFULL, o = idx / KFULL;
        float v;
        if (k < 1024) {
            int r = k >> 7, i = k & 127;
            v = 0.f;
            for (int b = 0; b < NBASES; ++b)
                v += comp[r * NBASES + b] * basis[(b * DIM + i) * DIM + o];
        } else {
            v = root[(k - 1024) * DIM + o];
        }
        WfullT[o * KFULL + k] = __float2bfloat16(v);
    } else if (idx < n_full + n_sq) {
        int t = idx - n_full; int k = t & 127, o = t >> 7;
        wrelT[o * DIM + k] = __float2bfloat16(w_rel[k * DIM + o]);
    } else if (idx < n_full + 2 * n_sq) {
        int t = idx - n_full - n_sq; int k = t & 127, o = t >> 7;
        wrootT[o * DIM + k] = __float2bfloat16(w_root[k * DIM + o]);
    }
}

// ---------------- fp32 -> bf16 node features (vectorized x4) ----------------
__global__ void conv_x(const float4* __restrict__ x4, ushort4* __restrict__ xb4, int n4) {
    int i = blockIdx.x * blockDim.x + threadIdx.x;
    if (i < n4) {
        float4 f = x4[i];
        ushort4 o;
        o.x = f2bu(f.x); o.y = f2bu(f.y); o.z = f2bu(f.z); o.w = f2bu(f.w);
        xb4[i] = o;
    }
}

// ---------------- counting sort by (dst*8+type) ----------------
__global__ void hist_kernel(const int* __restrict__ ei, const int* __restrict__ et,
                            int* __restrict__ deg) {
    int e = blockIdx.x * blockDim.x + threadIdx.x;
    if (e < N_EDGES) atomicAdd(&deg[ei[N_EDGES + e] * NREL + et[e]], 1);
}

__global__ void scan_blocks(const int* __restrict__ deg, int* __restrict__ segoff,
                            int* __restrict__ bsum, int n) {
    __shared__ int buf[256];
    int tid = threadIdx.x;
    int i = blockIdx.x * 256 + tid;
    int v = (i < n) ? deg[i] : 0;
    buf[tid] = v;
    __syncthreads();
#pragma unroll
    for (int o = 1; o < 256; o <<= 1) {
        int t = (tid >= o) ? buf[tid - o] : 0;
        __syncthreads();
        buf[tid] += t;
        __syncthreads();
    }
    if (i < n) segoff[i + 1] = buf[tid];
    if (tid == 255) bsum[blockIdx.x] = buf[255];
}

// single WAVE shuffle-scan of block sums -> exclusive (no barriers)
__global__ void scan_sums(int* __restrict__ bsum, int nb) {
    int lane = threadIdx.x;   // 64 threads
    int base = 0;
    for (int start = 0; start < nb; start += 64) {
        int i = start + lane;
        int v = (i < nb) ? bsum[i] : 0;
        int incl = v;
#pragma unroll
        for (int o = 1; o < 64; o <<= 1) {
            int t = __shfl_up(incl, o, 64);
            if (lane >= o) incl += t;
        }
        if (i < nb) bsum[i] = base + incl - v;   // exclusive
        base += __shfl(incl, 63, 64);
    }
}

__global__ void scan_add(int* __restrict__ segoff, const int* __restrict__ bsum, int n) {
    int i = blockIdx.x * 256 + threadIdx.x;
    if (i < n) segoff[i + 1] += bsum[blockIdx.x];
    if (i == 0) segoff[0] = 0;
}

// rec.x = src | (type<<16)
__global__ void scatter_kernel(const int* __restrict__ ei, const int* __restrict__ et,
                               const float* __restrict__ en, const int* __restrict__ segoff,
                               int* __restrict__ cur, uint2* __restrict__ rec) {
    int e = blockIdx.x * blockDim.x + threadIdx.x;
    if (e < N_EDGES) {
        int typ = et[e];
        int key = ei[N_EDGES + e] * NREL + typ;
        int p = segoff[key] + atomicAdd(&cur[key], 1);
        rec[p] = make_uint2((unsigned)ei[e] | ((unsigned)typ << 16), __float_as_uint(en[e]));
    }
}

// ---------------- typed aggregation: quarter-wave (16 lanes/node, 16 B/lane) ----------------
// 4 edges per gather instruction; flush accumulator at type boundaries (uniform within quad).
__global__ void agg1_kernel(const uint2* __restrict__ rec, const int* __restrict__ segoff,
                            const ushort* __restrict__ xb, ushort* __restrict__ agg) {
    int quad = threadIdx.x >> 4;              // 16 quads per block
    int node = blockIdx.x * 16 + quad;
    if (node >= N_NODES) return;
    int lane = threadIdx.x & 15;
    int base = node * NREL;
    int s = segoff[base], e = segoff[base + NREL];
    float acc[8] = {0.f, 0.f, 0.f, 0.f, 0.f, 0.f, 0.f, 0.f};
    int cur_t = 0;
    for (int chunk = s; chunk < e; chunk += 4) {
        int m = e - chunk; if (m > 4) m = 4;
        uint2 rr[4]; short8 vv[4];
#pragma unroll
        for (int j = 0; j < 4; ++j) if (j < m) rr[j] = rec[chunk + j];
#pragma unroll
        for (int j = 0; j < 4; ++j) if (j < m)
            vv[j] = *(const short8*)(xb + (size_t)(rr[j].x & 0xFFFFu) * 128 + lane * 8);
#pragma unroll
        for (int j = 0; j < 4; ++j) if (j < m) {
            int t = (int)(rr[j].x >> 16);
            if (t != cur_t) {   // uniform within quad; predicated across quads
                short8 o;
#pragma unroll
                for (int f = 0; f < 8; ++f) o[f] = (short)f2bu(acc[f]);
                *(short8*)(agg + (size_t)(base + cur_t) * 128 + lane * 8) = o;
                short8 z = {0, 0, 0, 0, 0, 0, 0, 0};
                for (int tt = cur_t + 1; tt < t; ++tt)
                    *(short8*)(agg + (size_t)(base + tt) * 128 + lane * 8) = z;
#pragma unroll
                for (int f = 0; f < 8; ++f) acc[f] = 0.f;
                cur_t = t;
            }
            float norm = __uint_as_float(rr[j].y);
#pragma unroll
            for (int f = 0; f < 8; ++f) acc[f] += norm * bu2f((ushort)vv[j][f]);
        }
    }
    {   // final flush + trailing zeros (handles degree-0 nodes too)
        short8 o;
#pragma unroll
        for (int f = 0; f < 8; ++f) o[f] = (short)f2bu(acc[f]);
        *(short8*)(agg + (size_t)(base + cur_t) * 128 + lane * 8) = o;
        short8 z = {0, 0, 0, 0, 0, 0, 0, 0};
        for (int tt = cur_t + 1; tt < NREL; ++tt)
            *(short8*)(agg + (size_t)(base + tt) * 128 + lane * 8) = z;
    }
}

// ---------------- GEMM: h[M,128](bf16) = [agg | xb][M,1152] @ WfullT^T + bias1 ----------------
__global__ __launch_bounds__(256) void gemm_h(const bf16* __restrict__ agg, const bf16* __restrict__ xb,
                                              const bf16* __restrict__ WfullT, const float* __restrict__ bias1,
                                              bf16* __restrict__ h, int M) {
    __shared__ ushort As[64][72];
    __shared__ ushort Bs[128][72];
    const ushort* Au_agg = (const ushort*)agg;
    const ushort* Au_x   = (const ushort*)xb;
    const ushort* Bu     = (const ushort*)WfullT;
    int tm = blockIdx.x * 64;
    int wave = threadIdx.x >> 6, lane = threadIdx.x & 63;
    int q = lane >> 4, mr = lane & 15;
    floatx4 zero = {0.f, 0.f, 0.f, 0.f};
    floatx4 acc[8] = {zero, zero, zero, zero, zero, zero, zero, zero};

    for (int kt = 0; kt < 18; ++kt) {
        if (kt) __syncthreads();
#pragma unroll
        for (int u = 0; u < 2; ++u) {
            int cc = threadIdx.x + u * 256;
            int row = cc >> 3, seg = cc & 7;
            int gr = tm + row;
            short8 av = {0, 0, 0, 0, 0, 0, 0, 0};
            if (gr < M) {
                if (kt < 16) av = *(const short8*)(Au_agg + (size_t)gr * 1024 + kt * 64 + seg * 8);
                else         av = *(const short8*)(Au_x   + (size_t)gr * 128 + (kt - 16) * 64 + seg * 8);
            }
            *(short8*)(&As[row][seg * 8]) = av;
        }
#pragma unroll
        for (int u = 0; u < 4; ++u) {
            int cc = threadIdx.x + u * 256;
            int row = cc >> 3, seg = cc & 7;
            short8 bv = *(const short8*)(Bu + (size_t)row * KFULL + kt * 64 + seg * 8);
            *(short8*)(&Bs[row][seg * 8]) = bv;
        }
        __syncthreads();
#pragma unroll
        for (int kh = 0; kh < 2; ++kh) {
            short8 a = *(const short8*)(&As[wave * 16 + mr][q * 8 + kh * 32]);
#pragma unroll
            for (int nt = 0; nt < 8; ++nt) {
                short8 b = *(const short8*)(&Bs[nt * 16 + mr][q * 8 + kh * 32]);
                acc[nt] = __builtin_amdgcn_mfma_f32_16x16x32_bf16(a, b, acc[nt], 0, 0, 0);
            }
        }
    }
#pragma unroll
    for (int nt = 0; nt < 8; ++nt)
#pragma unroll
        for (int r4 = 0; r4 < 4; ++r4) {
            int row = tm + wave * 16 + q * 4 + r4;
            int col = nt * 16 + mr;
            if (row < M) h[(size_t)row * 128 + col] = __float2bfloat16(acc[nt][r4] + bias1[col]);
        }
}

// ---------------- layer-2 segment sum: quarter-wave (16 lanes/node, 16 B/lane) ----------------
__global__ void seg2_kernel(const uint2* __restrict__ rec, const int* __restrict__ segoff,
                            const ushort* __restrict__ h, ushort* __restrict__ out2) {
    int quad = threadIdx.x >> 4;
    int node = blockIdx.x * 16 + quad;
    if (node >= N_NODES) return;
    int lane = threadIdx.x & 15;
    int s = segoff[node * NREL], e = segoff[node * NREL + NREL];
    float acc[8] = {0.f, 0.f, 0.f, 0.f, 0.f, 0.f, 0.f, 0.f};
    for (int chunk = s; chunk < e; chunk += 4) {
        int m = e - chunk; if (m > 4) m = 4;
        uint2 rr[4]; short8 vv[4];
#pragma unroll
        for (int j = 0; j < 4; ++j) if (j < m) rr[j] = rec[chunk + j];
#pragma unroll
        for (int j = 0; j < 4; ++j) if (j < m)
            vv[j] = *(const short8*)(h + (size_t)(rr[j].x & 0xFFFFu) * 128 + lane * 8);
#pragma unroll
        for (int j = 0; j < 4; ++j) if (j < m)
#pragma unroll
            for (int f = 0; f < 8; ++f) acc[f] += bu2f((ushort)vv[j][f]);
    }
    short8 o;
#pragma unroll
    for (int f = 0; f < 8; ++f) o[f] = (short)f2bu(acc[f]);
    *(short8*)(out2 + (size_t)node * 128 + lane * 8) = o;
}

// ---------------- final GEMM: out[M,128](f32) = agg2nd@w_rel + h@w_root + b_rel ----------------
__global__ __launch_bounds__(256) void gemm2_kernel(const bf16* __restrict__ A1, const bf16* __restrict__ B1T,
                                                    const bf16* __restrict__ A2, const bf16* __restrict__ B2T,
                                                    const float* __restrict__ brel, float* __restrict__ out, int M) {
    __shared__ ushort As[64][136];
    __shared__ ushort Bs[64][136];
    int tm = blockIdx.x * 64, tn = blockIdx.y * 64;
    int wave = threadIdx.x >> 6, lane = threadIdx.x & 63;
    int q = lane >> 4, mr = lane & 15;
    floatx4 zero = {0.f, 0.f, 0.f, 0.f};
    floatx4 acc[4] = {zero, zero, zero, zero};

    for (int phase = 0; phase < 2; ++phase) {
        const ushort* Au = (const ushort*)(phase ? A2 : A1);
        const ushort* Bu = (const ushort*)(phase ? B2T : B1T);
        if (phase) __syncthreads();
        for (int c = threadIdx.x; c < 64 * 16; c += 256) {
            int row = c >> 4, seg = c & 15;
            int gr = tm + row;
            short8 av = {0, 0, 0, 0, 0, 0, 0, 0};
            if (gr < M) av = *(const short8*)(Au + (size_t)gr * 128 + seg * 8);
            *(short8*)(&As[row][seg * 8]) = av;
            short8 bv = *(const short8*)(Bu + (size_t)(tn + row) * 128 + seg * 8);
            *(short8*)(&Bs[row][seg * 8]) = bv;
        }
        __syncthreads();
#pragma unroll
        for (int kt = 0; kt < 4; ++kt) {
            short8 a = *(const short8*)(&As[wave * 16 + mr][q * 8 + kt * 32]);
#pragma unroll
            for (int nt = 0; nt < 4; ++nt) {
                short8 b = *(const short8*)(&Bs[nt * 16 + mr][q * 8 + kt * 32]);
                acc[nt] = __builtin_amdgcn_mfma_f32_16x16x32_bf16(a, b, acc[nt], 0, 0, 0);
            }
        }
    }
#pragma unroll
    for (int nt = 0; nt < 4; ++nt)
#pragma unroll
        for (int r4 = 0; r4 < 4; ++r4) {
            int row = tm + wave * 16 + q * 4 + r4;
            int col = tn + nt * 16 + mr;
            if (row < M) out[(size_t)row * 128 + col] = acc[nt][r4] + brel[col];
        }
}

extern "C" void kernel_launch(void* const* d_in, const int* in_sizes, int n_in,
                              void* d_out, int out_size, void* d_ws, size_t ws_size,
                              hipStream_t stream) {
    const float* x      = (const float*)d_in[0];
    const int*   ei     = (const int*)d_in[1];
    const int*   et     = (const int*)d_in[2];
    const float* en     = (const float*)d_in[3];
    const float* basis  = (const float*)d_in[4];
    const float* comp   = (const float*)d_in[5];
    const float* root   = (const float*)d_in[6];
    const float* bias1  = (const float*)d_in[7];
    const float* w_rel  = (const float*)d_in[8];
    const float* b_rel  = (const float*)d_in[9];
    const float* w_root = (const float*)d_in[10];
    float* out = (float*)d_out;

    char* ws = (char*)d_ws;
    size_t off = 0;
    auto alloc = [&](size_t bytes) { size_t o = off; off += (bytes + 255) & ~(size_t)255; return o; };

    size_t o_deg    = alloc((size_t)NKEYS * 4);      // zeroed
    size_t o_cur    = alloc((size_t)NKEYS * 4);      // zeroed (contiguous with deg)
    size_t o_segoff = alloc((size_t)(NKEYS + 1) * 4);
    size_t o_bsum   = alloc((size_t)SCAN_NB * 4);
    size_t o_rec    = alloc((size_t)N_EDGES * 8);
    size_t o_wfull  = alloc((size_t)DIM * KFULL * 2);
    size_t o_wrel   = alloc((size_t)DIM * DIM * 2);
    size_t o_wroot  = alloc((size_t)DIM * DIM * 2);
    size_t o_xb     = alloc((size_t)N_NODES * DIM * 2);
    size_t o_agg    = alloc((size_t)N_NODES * NREL * DIM * 2);   // 102.4 MB
    size_t o_hb     = alloc((size_t)N_NODES * DIM * 2);
    size_t o_agg2   = alloc((size_t)N_NODES * DIM * 2);

    int*   deg    = (int*)(ws + o_deg);
    int*   cur    = (int*)(ws + o_cur);
    int*   segoff = (int*)(ws + o_segoff);
    int*   bsum   = (int*)(ws + o_bsum);
    uint2* rec    = (uint2*)(ws + o_rec);
    bf16*  wfull  = (bf16*)(ws + o_wfull);
    bf16*  wrelT  = (bf16*)(ws + o_wrel);
    bf16*  wrootT = (bf16*)(ws + o_wroot);
    bf16*  xb     = (bf16*)(ws + o_xb);
    bf16*  agg    = (bf16*)(ws + o_agg);
    bf16*  hb     = (bf16*)(ws + o_hb);
    bf16*  agg2   = (bf16*)(ws + o_agg2);

    hipMemsetAsync(ws + o_deg, 0, o_segoff - o_deg, stream);

    {   // weights
        int total = DIM * KFULL + 2 * DIM * DIM;
        prep_weights<<<(total + 255) / 256, 256, 0, stream>>>(basis, comp, root, w_rel, w_root,
                                                              wfull, wrelT, wrootT);
    }
    {   // bf16 features (x4 vectorized)
        int n4 = N_NODES * DIM / 4;
        conv_x<<<(n4 + 255) / 256, 256, 0, stream>>>((const float4*)x, (ushort4*)xb, n4);
    }
    // counting sort by (dst*8+type)
    hist_kernel<<<(N_EDGES + 255) / 256, 256, 0, stream>>>(ei, et, deg);
    scan_blocks<<<SCAN_NB, 256, 0, stream>>>(deg, segoff, bsum, NKEYS);
    scan_sums<<<1, 64, 0, stream>>>(bsum, SCAN_NB);
    scan_add<<<SCAN_NB, 256, 0, stream>>>(segoff, bsum, NKEYS);
    scatter_kernel<<<(N_EDGES + 255) / 256, 256, 0, stream>>>(ei, et, en, segoff, cur, rec);

    // typed aggregation (quarter-wave gather: 4 rows / instruction)
    agg1_kernel<<<(N_NODES + 15) / 16, 256, 0, stream>>>(rec, segoff, (const ushort*)xb, (ushort*)agg);
    // h = [agg | xb] @ Wfull + bias1
    gemm_h<<<(N_NODES + 63) / 64, 256, 0, stream>>>(agg, xb, wfull, bias1, hb, N_NODES);
    // layer 2 aggregation (quarter-wave gather)
    seg2_kernel<<<(N_NODES + 15) / 16, 256, 0, stream>>>(rec, segoff, (const ushort*)hb, (ushort*)agg2);
    // out = agg2 @ w_rel + h @ w_root + b_rel
    {
        dim3 grid((N_NODES + 63) / 64, DIM / 64);
        gemm2_kernel<<<grid, 256, 0, stream>>>(agg2, wrelT, hb, wrootT, b_rel, out, N_NODES);
    }
}